// Round 3
// baseline (400.573 us; speedup 1.0000x reference)
//
#include <hip/hip_runtime.h>

#define FI 256
#define FH 64
#define FO 128
#define ASORT_CHUNK 2048
// ushort-view row stride 256: bf16 h1 at ushort[128..191], bf16 hrelu at [192..255],
// fp32 combined at float[0..63].

__device__ __forceinline__ ushort f2bf(float x) {   // fp32 -> bf16 RNE
    unsigned b = __float_as_uint(x);
    b += 0x7fffu + ((b >> 16) & 1u);
    return (ushort)(b >> 16);
}
__device__ __forceinline__ float bf2f(ushort u) {
    return __uint_as_float(((unsigned)u) << 16);
}

// ---------------- fallback-path small kernels ----------------

__global__ void zero_i32(int* __restrict__ p, int n) {
    int i = blockIdx.x * 256 + threadIdx.x;
    if (i < n) p[i] = 0;
}

__global__ void deg_cnt_kernel(const int* __restrict__ dst, int* __restrict__ cnt, int E) {
    int base = blockIdx.x * 1024 + threadIdx.x;
    #pragma unroll
    for (int q = 0; q < 4; ++q) {
        int e = base + q * 256;
        if (e < E) atomicAdd(&cnt[dst[e]], 1);
    }
}

__global__ void dinv_kernel(const int* __restrict__ cnt, float* __restrict__ dinv, int N) {
    int i = blockIdx.x * 256 + threadIdx.x;
    if (i < N) dinv[i] = rsqrtf((float)cnt[i] + 1.0f);
}

// ---------------- CSR build: atomic-free histogram + binned counting sort ----------------

// Stage 0: per-block 256-bucket LDS histogram of dst>>8; coalesced partial rows,
// NO global atomics. partial[block*256 + b].
__global__ __launch_bounds__(256) void hist_part_kernel(const int* __restrict__ dst,
                                                        int* __restrict__ partial, int E) {
    __shared__ int lcnt[256];
    int t = threadIdx.x;
    int base = blockIdx.x * ASORT_CHUNK;
    lcnt[t] = 0;
    __syncthreads();
    #pragma unroll
    for (int j = 0; j < 8; ++j) {
        int e = base + j * 256 + t;
        if (e < E) atomicAdd(&lcnt[((unsigned)dst[e]) >> 8], 1);
    }
    __syncthreads();
    partial[blockIdx.x * 256 + t] = lcnt[t];
}

// Stage 1 (1 block): column-sum partials (coalesced), exclusive scan -> bucket_base[257],
// seed bucket_pos.
__global__ __launch_bounds__(256) void bucket_scan_kernel(const int* __restrict__ partial,
                                                          int* __restrict__ bucket_base,
                                                          int* __restrict__ bucket_pos,
                                                          int nblk, int E) {
    __shared__ int sc[256];
    int t = threadIdx.x;
    int sum = 0;
    for (int k = 0; k < nblk; ++k) sum += partial[k * 256 + t];
    sc[t] = sum;
    __syncthreads();
    for (int off = 1; off < 256; off <<= 1) {
        int u = (t >= off) ? sc[t - off] : 0;
        __syncthreads();
        sc[t] += u;
        __syncthreads();
    }
    int excl = sc[t] - sum;
    bucket_base[t] = excl;
    bucket_pos[t]  = excl;
    if (t == 255) bucket_base[256] = sc[255];   // == E
}

// Pass A: per-block LDS counting sort by bucket (dst>>8), flushed as contiguous runs
// into the bucket's region. Record packs src|dst<<16 (4B, N<=65536).
__global__ __launch_bounds__(256) void binA_kernel(const int* __restrict__ src,
                                                   const int* __restrict__ dst,
                                                   int* __restrict__ bucket_pos,
                                                   unsigned* __restrict__ binned, int E) {
    __shared__ int lcnt[256];
    __shared__ int lbase[256];
    __shared__ int gbase[256];
    __shared__ int sc[256];
    __shared__ unsigned sorted[ASORT_CHUNK];
    int t = threadIdx.x;
    int base = blockIdx.x * ASORT_CHUNK;
    lcnt[t] = 0;
    __syncthreads();
    unsigned pk[8];
    short bb[8];
    short mi[8];
    #pragma unroll
    for (int j = 0; j < 8; ++j) {
        int e = base + j * 256 + t;
        if (e < E) {
            unsigned s = (unsigned)src[e];
            unsigned d = (unsigned)dst[e];
            pk[j] = s | (d << 16);
            int b = (int)(d >> 8);
            bb[j] = (short)b;
            mi[j] = (short)atomicAdd(&lcnt[b], 1);
        } else {
            bb[j] = -1;
        }
    }
    __syncthreads();
    int v = lcnt[t];
    sc[t] = v;
    __syncthreads();
    #pragma unroll
    for (int off = 1; off < 256; off <<= 1) {
        int u = (t >= off) ? sc[t - off] : 0;
        __syncthreads();
        sc[t] += u;
        __syncthreads();
    }
    lbase[t] = sc[t] - v;                       // exclusive prefix
    if (v > 0) gbase[t] = atomicAdd(&bucket_pos[t], v);
    __syncthreads();
    #pragma unroll
    for (int j = 0; j < 8; ++j)
        if (bb[j] >= 0) sorted[lbase[(int)bb[j]] + (int)mi[j]] = pk[j];
    int tot = sc[255];
    __syncthreads();
    for (int i = t; i < tot; i += 256) {
        unsigned vv = sorted[i];
        int b = (int)(vv >> 24);                // dst>>8 (dst < 65536)
        binned[gbase[b] + (i - lbase[b])] = vv;
    }
}

// Pass B: one block per bucket. Pass 1: LDS per-node histogram + scan -> writes
// row_start/cnt/dinv for its 256 nodes (no global atomics). Pass 2: scatter rec4
// within the bucket's ~32KB region (L1/L2-hot second read). rec4[p] = src.
__global__ __launch_bounds__(256) void binB_kernel(const int* __restrict__ bucket_base,
                                                   const unsigned* __restrict__ binned,
                                                   int* __restrict__ rec4,
                                                   int* __restrict__ row_start,
                                                   int* __restrict__ cnt,
                                                   float* __restrict__ dinv, int N) {
    __shared__ int lcnt[256];
    __shared__ int sc[256];
    __shared__ int lstart[256];
    __shared__ int loff[256];
    int t = threadIdx.x;
    int d0 = blockIdx.x << 8;
    int start = bucket_base[blockIdx.x];
    int end   = bucket_base[blockIdx.x + 1];
    lcnt[t] = 0;
    __syncthreads();
    // pass 1: per-node histogram of this bucket's edges
    for (int i = start + t; i < end; i += 256)
        atomicAdd(&lcnt[(binned[i] >> 16) & 0xffu], 1);
    __syncthreads();
    int v = lcnt[t];
    sc[t] = v;
    __syncthreads();
    for (int off = 1; off < 256; off <<= 1) {
        int u = (t >= off) ? sc[t - off] : 0;
        __syncthreads();
        sc[t] += u;
        __syncthreads();
    }
    int st = start + sc[t] - v;                  // row start for node d0+t
    lstart[t] = st;
    loff[t] = 0;
    if (d0 + t < N) {
        row_start[d0 + t] = st;
        cnt[d0 + t] = v;
        dinv[d0 + t] = rsqrtf((float)v + 1.0f);
    }
    __syncthreads();
    // pass 2: scatter src into CSR slots
    int i = start + t;
    for (; i + 768 < end; i += 1024) {
        unsigned v0 = binned[i];
        unsigned v1 = binned[i + 256];
        unsigned v2 = binned[i + 512];
        unsigned v3 = binned[i + 768];
        int dA = (int)((v0 >> 16) & 0xffu); int kA = atomicAdd(&loff[dA], 1);
        rec4[lstart[dA] + kA] = (int)(v0 & 0xffffu);
        int dB = (int)((v1 >> 16) & 0xffu); int kB = atomicAdd(&loff[dB], 1);
        rec4[lstart[dB] + kB] = (int)(v1 & 0xffffu);
        int dC = (int)((v2 >> 16) & 0xffu); int kC = atomicAdd(&loff[dC], 1);
        rec4[lstart[dC] + kC] = (int)(v2 & 0xffffu);
        int dD = (int)((v3 >> 16) & 0xffu); int kD = atomicAdd(&loff[dD], 1);
        rec4[lstart[dD] + kD] = (int)(v3 & 0xffffu);
    }
    for (; i < end; i += 256) {
        unsigned v4 = binned[i];
        int d = (int)((v4 >> 16) & 0xffu);
        int k = atomicAdd(&loff[d], 1);
        rec4[lstart[d] + k] = (int)(v4 & 0xffffu);
    }
}

// ---------------- gather-side aggregation: 4 edges per wave-instruction ----------------
// Wave = 1 node. Lane L: g = L>>4 (edge slot), q = L&15 (feature quad, 4 bf16 = 8B).
// rec4 holds src only; w = dinv[src]*dinv[node] recomputed (dinv is L2-resident).

// layer 1: gather bf16 h1 (cols [128..191]); write bf16 hrelu = relu(acc + dv^2*own + b1)
__global__ void gather_relu_kernel(const int* __restrict__ rec4, const int* __restrict__ row_start,
                                   const int* __restrict__ cnt, const float* __restrict__ dinv,
                                   const float* __restrict__ b1, float* __restrict__ out, int N) {
    int node = blockIdx.x * 4 + (threadIdx.x >> 6);
    if (node >= N) return;
    int L = threadIdx.x & 63;
    int g = L >> 4;
    int q = L & 15;
    const ushort* hb = (const ushort*)out;
    int beg = row_start[node];
    int n   = cnt[node];
    float dvd = dinv[node];
    float4 acc = make_float4(0.f, 0.f, 0.f, 0.f);
    for (int i = 0; i < n; i += 16) {
        #pragma unroll
        for (int u = 0; u < 4; ++u) {
            int idx = i + u * 4 + g;
            int sidx = node;
            float w = 0.f;
            if (idx < n) {
                sidx = rec4[beg + idx];
                w = dinv[sidx] * dvd;
            }
            uint2 hv = *(const uint2*)(hb + (size_t)sidx * 256 + 128 + q * 4);
            acc.x = fmaf(bf2f((ushort)(hv.x & 0xffffu)), w, acc.x);
            acc.y = fmaf(bf2f((ushort)(hv.x >> 16)),     w, acc.y);
            acc.z = fmaf(bf2f((ushort)(hv.y & 0xffffu)), w, acc.z);
            acc.w = fmaf(bf2f((ushort)(hv.y >> 16)),     w, acc.w);
        }
    }
    acc.x += __shfl_xor(acc.x, 16, 64);
    acc.y += __shfl_xor(acc.y, 16, 64);
    acc.z += __shfl_xor(acc.z, 16, 64);
    acc.w += __shfl_xor(acc.w, 16, 64);
    acc.x += __shfl_xor(acc.x, 32, 64);
    acc.y += __shfl_xor(acc.y, 32, 64);
    acc.z += __shfl_xor(acc.z, 32, 64);
    acc.w += __shfl_xor(acc.w, 32, 64);
    if (L < 16) {
        float dv2 = dvd * dvd;
        uint2 ho = *(const uint2*)(hb + (size_t)node * 256 + 128 + q * 4);
        float4 b = *(const float4*)&b1[q * 4];
        float r0 = fmaxf(acc.x + dv2 * bf2f((ushort)(ho.x & 0xffffu)) + b.x, 0.f);
        float r1 = fmaxf(acc.y + dv2 * bf2f((ushort)(ho.x >> 16))     + b.y, 0.f);
        float r2 = fmaxf(acc.z + dv2 * bf2f((ushort)(ho.y & 0xffffu)) + b.z, 0.f);
        float r3 = fmaxf(acc.w + dv2 * bf2f((ushort)(ho.y >> 16))     + b.w, 0.f);
        ushort4 st = {f2bf(r0), f2bf(r1), f2bf(r2), f2bf(r3)};
        *(ushort4*)((ushort*)out + (size_t)node * 256 + 192 + q * 4) = st;
    }
}

// layer 2: gather bf16 hrelu (cols [192..255]); write fp32 combined to float[0..63]
__global__ void gather_comb_kernel(const int* __restrict__ rec4, const int* __restrict__ row_start,
                                   const int* __restrict__ cnt, const float* __restrict__ dinv,
                                   float* __restrict__ out, int N) {
    int node = blockIdx.x * 4 + (threadIdx.x >> 6);
    if (node >= N) return;
    int L = threadIdx.x & 63;
    int g = L >> 4;
    int q = L & 15;
    const ushort* hb = (const ushort*)out;
    int beg = row_start[node];
    int n   = cnt[node];
    float dvd = dinv[node];
    float4 acc = make_float4(0.f, 0.f, 0.f, 0.f);
    for (int i = 0; i < n; i += 16) {
        #pragma unroll
        for (int u = 0; u < 4; ++u) {
            int idx = i + u * 4 + g;
            int sidx = node;
            float w = 0.f;
            if (idx < n) {
                sidx = rec4[beg + idx];
                w = dinv[sidx] * dvd;
            }
            uint2 hv = *(const uint2*)(hb + (size_t)sidx * 256 + 192 + q * 4);
            acc.x = fmaf(bf2f((ushort)(hv.x & 0xffffu)), w, acc.x);
            acc.y = fmaf(bf2f((ushort)(hv.x >> 16)),     w, acc.y);
            acc.z = fmaf(bf2f((ushort)(hv.y & 0xffffu)), w, acc.z);
            acc.w = fmaf(bf2f((ushort)(hv.y >> 16)),     w, acc.w);
        }
    }
    acc.x += __shfl_xor(acc.x, 16, 64);
    acc.y += __shfl_xor(acc.y, 16, 64);
    acc.z += __shfl_xor(acc.z, 16, 64);
    acc.w += __shfl_xor(acc.w, 16, 64);
    acc.x += __shfl_xor(acc.x, 32, 64);
    acc.y += __shfl_xor(acc.y, 32, 64);
    acc.z += __shfl_xor(acc.z, 32, 64);
    acc.w += __shfl_xor(acc.w, 32, 64);
    if (L < 16) {
        float dv2 = dvd * dvd;
        uint2 ho = *(const uint2*)(hb + (size_t)node * 256 + 192 + q * 4);
        float4 o;
        o.x = acc.x + dv2 * bf2f((ushort)(ho.x & 0xffffu));
        o.y = acc.y + dv2 * bf2f((ushort)(ho.x >> 16));
        o.z = acc.z + dv2 * bf2f((ushort)(ho.y & 0xffffu));
        o.w = acc.w + dv2 * bf2f((ushort)(ho.y >> 16));
        *(float4*)&out[(size_t)node * FO + q * 4] = o;
    }
}

// ---------------- dense kernels: register-tiled SGEMM ----------------

// mm1: h1 = x @ W1 -> bf16 at ushort[128..191] of each row (plain, unscaled).
__global__ __launch_bounds__(256) void mm1_tiled(const float* __restrict__ x,
                                                 const float* __restrict__ W1,
                                                 float* __restrict__ out, int N) {
    __shared__ float xs[32][128];
    __shared__ float ws[32][64];
    int tid = threadIdx.x;
    int R0  = blockIdx.x * 128;
    int ty  = tid >> 3;
    int tx  = tid & 7;
    float acc[4][8];
    #pragma unroll
    for (int i = 0; i < 4; ++i)
        #pragma unroll
        for (int j = 0; j < 8; ++j) acc[i][j] = 0.f;

    int sr = tid >> 1;
    int sk = (tid & 1) * 16;
    bool row_ok = (R0 + sr) < N;
    const float* xrow = x + (size_t)(R0 + sr) * FI;

    for (int k0 = 0; k0 < FI; k0 += 32) {
        __syncthreads();
        #pragma unroll
        for (int q = 0; q < 4; ++q) {
            float4 v = row_ok ? *(const float4*)&xrow[k0 + sk + q * 4]
                              : make_float4(0.f, 0.f, 0.f, 0.f);
            xs[sk + q * 4 + 0][sr] = v.x;
            xs[sk + q * 4 + 1][sr] = v.y;
            xs[sk + q * 4 + 2][sr] = v.z;
            xs[sk + q * 4 + 3][sr] = v.w;
        }
        {
            int f = tid * 2;
            *(float4*)&ws[0][0 + f * 4]     = *(const float4*)&W1[(size_t)k0 * 64 + f * 4];
            *(float4*)&ws[0][0 + f * 4 + 4] = *(const float4*)&W1[(size_t)k0 * 64 + f * 4 + 4];
        }
        __syncthreads();
        #pragma unroll 4
        for (int k = 0; k < 32; ++k) {
            float4 a  = *(const float4*)&xs[k][ty * 4];
            float4 bl = *(const float4*)&ws[k][tx * 4];
            float4 bh = *(const float4*)&ws[k][32 + tx * 4];
            float av[4] = {a.x, a.y, a.z, a.w};
            float bv[8] = {bl.x, bl.y, bl.z, bl.w, bh.x, bh.y, bh.z, bh.w};
            #pragma unroll
            for (int i = 0; i < 4; ++i)
                #pragma unroll
                for (int j = 0; j < 8; ++j)
                    acc[i][j] = fmaf(av[i], bv[j], acc[i][j]);
        }
    }
    #pragma unroll
    for (int i = 0; i < 4; ++i) {
        int row = R0 + ty * 4 + i;
        if (row < N) {
            ushort* ob = (ushort*)out + (size_t)row * 256 + 128;
            ushort4 lo = {f2bf(acc[i][0]), f2bf(acc[i][1]), f2bf(acc[i][2]), f2bf(acc[i][3])};
            ushort4 hi = {f2bf(acc[i][4]), f2bf(acc[i][5]), f2bf(acc[i][6]), f2bf(acc[i][7])};
            *(ushort4*)&ob[tx * 4]      = lo;
            *(ushort4*)&ob[32 + tx * 4] = hi;
        }
    }
}

// mm2: out_row = combined(float[0..63]) @ W2 + b2, in place.
__global__ __launch_bounds__(256) void mm2_tiled(const float* __restrict__ W2,
                                                 const float* __restrict__ b2,
                                                 float* __restrict__ out, int N) {
    __shared__ float xs[64][68];
    __shared__ float ws[64][128];
    int tid = threadIdx.x;
    int R0  = blockIdx.x * 64;
    int ty  = tid >> 4;
    int tx  = tid & 15;

    {
        int sr = tid >> 2;
        int l4 = tid & 3;
        int grow = R0 + sr;
        bool ok = grow < N;
        const float* orow = out + (size_t)grow * FO;
        #pragma unroll
        for (int q = 0; q < 4; ++q) {
            int j0 = (l4 + 4 * q) * 4;
            float4 a = ok ? *(const float4*)&orow[j0] : make_float4(0.f, 0.f, 0.f, 0.f);
            xs[j0 + 0][sr] = a.x;
            xs[j0 + 1][sr] = a.y;
            xs[j0 + 2][sr] = a.z;
            xs[j0 + 3][sr] = a.w;
        }
    }
    #pragma unroll
    for (int q = 0; q < 8; ++q) {
        int f = tid + q * 256;
        *(float4*)&ws[f >> 5][(f & 31) * 4] = *(const float4*)&W2[(size_t)f * 4];
    }
    __syncthreads();

    float acc[4][8];
    #pragma unroll
    for (int i = 0; i < 4; ++i)
        #pragma unroll
        for (int j = 0; j < 8; ++j) acc[i][j] = 0.f;

    #pragma unroll 4
    for (int k = 0; k < FH; ++k) {
        float4 a  = *(const float4*)&xs[k][ty * 4];
        float4 bl = *(const float4*)&ws[k][tx * 4];
        float4 bh = *(const float4*)&ws[k][64 + tx * 4];
        float av[4] = {a.x, a.y, a.z, a.w};
        float bv[8] = {bl.x, bl.y, bl.z, bl.w, bh.x, bh.y, bh.z, bh.w};
        #pragma unroll
        for (int i = 0; i < 4; ++i)
            #pragma unroll
            for (int j = 0; j < 8; ++j)
                acc[i][j] = fmaf(av[i], bv[j], acc[i][j]);
    }

    float4 b2l = *(const float4*)&b2[tx * 4];
    float4 b2h = *(const float4*)&b2[64 + tx * 4];
    #pragma unroll
    for (int i = 0; i < 4; ++i) {
        int row = R0 + ty * 4 + i;
        if (row < N) {
            float* o = out + (size_t)row * FO;
            *(float4*)&o[tx * 4] = make_float4(acc[i][0] + b2l.x, acc[i][1] + b2l.y,
                                               acc[i][2] + b2l.z, acc[i][3] + b2l.w);
            *(float4*)&o[64 + tx * 4] = make_float4(acc[i][4] + b2h.x, acc[i][5] + b2h.y,
                                                    acc[i][6] + b2h.z, acc[i][7] + b2h.w);
        }
    }
}

// ---------------- fallback (atomic scatter) pieces — all fp32 ----------------

__global__ void expand_hs1_kernel(float* __restrict__ out, int N) {
    int row = blockIdx.x * 4 + (threadIdx.x >> 6);
    if (row >= N) return;
    int lane = threadIdx.x & 63;
    float v = bf2f(((const ushort*)out)[(size_t)row * 256 + 128 + lane]);
    out[(size_t)row * FO + FH + lane] = v;
}

__global__ void zero_half_kernel(float* __restrict__ out, int half, int N) {
    int i = blockIdx.x * 256 + threadIdx.x;
    if (i >= N * FH) return;
    out[(size_t)(i >> 6) * FO + half + (i & 63)] = 0.f;
}

__global__ void scatter_half_kernel(const int* __restrict__ src, const int* __restrict__ dst,
                                    const float* __restrict__ dinv, float* __restrict__ out,
                                    int rh, int wh, int E) {
    int e = blockIdx.x * 4 + (threadIdx.x >> 6);
    if (e >= E) return;
    int lane = threadIdx.x & 63;
    int s = src[e];
    int d = dst[e];
    float w = dinv[s] * dinv[d];
    atomicAdd(&out[(size_t)d * FO + wh + lane], out[(size_t)s * FO + rh + lane] * w);
}

// lower = relu(lower_agg + dv^2*upper_own + b1)
__global__ void finish1_kernel(float* __restrict__ out, const float* __restrict__ dinv,
                               const float* __restrict__ b1, int N) {
    int i = blockIdx.x * 256 + threadIdx.x;
    if (i >= N * FH) return;
    int row = i >> 6;
    int c   = i & 63;
    size_t base = (size_t)row * FO;
    float dv = dinv[row];
    out[base + c] = fmaxf(out[base + c] + dv * dv * out[base + FH + c] + b1[c], 0.f);
}

// lower = upper_agg + dv^2*lower_own   (combined for mm2)
__global__ void finish2_kernel(float* __restrict__ out, const float* __restrict__ dinv, int N) {
    int i = blockIdx.x * 256 + threadIdx.x;
    if (i >= N * FH) return;
    int row = i >> 6;
    int c   = i & 63;
    size_t base = (size_t)row * FO;
    float dv = dinv[row];
    out[base + c] = out[base + FH + c] + dv * dv * out[base + c];
}

extern "C" void kernel_launch(void* const* d_in, const int* in_sizes, int n_in,
                              void* d_out, int out_size, void* d_ws, size_t ws_size,
                              hipStream_t stream) {
    const float* x  = (const float*)d_in[0];
    const int*   ei = (const int*)d_in[1];
    const float* W1 = (const float*)d_in[2];
    const float* b1 = (const float*)d_in[3];
    const float* W2 = (const float*)d_in[4];
    const float* b2 = (const float*)d_in[5];
    float* out = (float*)d_out;

    int N = in_sizes[0] / FI;     // 50000
    int E = in_sizes[1] / 2;      // 1600000
    const int* src = ei;
    const int* dst = ei + E;

    char* w = (char*)d_ws;
    float* dinv        = (float*)w;      w += (size_t)N * 4;
    int*   cnt         = (int*)w;        w += (size_t)N * 4;
    int*   row_start   = (int*)w;        w += (size_t)N * 4;
    int*   bucket_pos  = (int*)w;        w += 256 * 4;
    int*   bucket_base = (int*)w;        w += 260 * 4;
    unsigned* binned   = (unsigned*)w;   w += (size_t)E * 4;
    int*   rec4        = (int*)w;        w += (size_t)E * 4;
    size_t need = (size_t)(w - (char*)d_ws);   // ~13.4 MB

    int nblkA = (E + ASORT_CHUNK - 1) / ASORT_CHUNK;   // 782
    int nbk   = (N + 255) >> 8;                        // 196 buckets for N=50000
    // partial histograms alias rec4 (dead until binB): nblkA*256 ints <= E ints.
    int* partial = rec4;

    if (ws_size >= need && N <= 65536 && (size_t)nblkA * 256 <= (size_t)E) {
        hist_part_kernel<<<nblkA, 256, 0, stream>>>(dst, partial, E);
        bucket_scan_kernel<<<1, 256, 0, stream>>>(partial, bucket_base, bucket_pos, nblkA, E);
        binA_kernel<<<nblkA, 256, 0, stream>>>(src, dst, bucket_pos, binned, E);
        binB_kernel<<<nbk, 256, 0, stream>>>(bucket_base, binned, rec4, row_start, cnt, dinv, N);

        mm1_tiled<<<(N + 127) / 128, 256, 0, stream>>>(x, W1, out, N);
        gather_relu_kernel<<<(N + 3) / 4, 256, 0, stream>>>(rec4, row_start, cnt, dinv, b1, out, N);
        gather_comb_kernel<<<(N + 3) / 4, 256, 0, stream>>>(rec4, row_start, cnt, dinv, out, N);
        mm2_tiled<<<(N + 63) / 64, 256, 0, stream>>>(W2, b2, out, N);
    } else {
        // fallback: atomic scatter path, all fp32
        zero_i32<<<(N + 255) / 256, 256, 0, stream>>>(cnt, N);
        deg_cnt_kernel<<<(E + 1023) / 1024, 256, 0, stream>>>(dst, cnt, E);
        dinv_kernel<<<(N + 255) / 256, 256, 0, stream>>>(cnt, dinv, N);
        mm1_tiled<<<(N + 127) / 128, 256, 0, stream>>>(x, W1, out, N);
        expand_hs1_kernel<<<(N + 3) / 4, 256, 0, stream>>>(out, N);
        zero_half_kernel<<<((N * FH) + 255) / 256, 256, 0, stream>>>(out, 0, N);
        scatter_half_kernel<<<(E + 3) / 4, 256, 0, stream>>>(src, dst, dinv, out, FH, 0, E);
        finish1_kernel<<<((N * FH) + 255) / 256, 256, 0, stream>>>(out, dinv, b1, N);
        zero_half_kernel<<<((N * FH) + 255) / 256, 256, 0, stream>>>(out, FH, N);
        scatter_half_kernel<<<(E + 3) / 4, 256, 0, stream>>>(src, dst, dinv, out, 0, FH, E);
        finish2_kernel<<<((N * FH) + 255) / 256, 256, 0, stream>>>(out, dinv, N);
        mm2_tiled<<<(N + 63) / 64, 256, 0, stream>>>(W2, b2, out, N);
    }
}

// Round 4
// 318.151 us; speedup vs baseline: 1.2591x; 1.2591x over previous
//
#include <hip/hip_runtime.h>

#define FI 256
#define FH 64
#define FO 128
#define ASORT_CHUNK 2048
// ushort-view row stride 256: bf16 h1 at ushort[128..191], bf16 hrelu at [192..255],
// fp32 combined at float[0..63].

__device__ __forceinline__ ushort f2bf(float x) {   // fp32 -> bf16 RNE
    unsigned b = __float_as_uint(x);
    b += 0x7fffu + ((b >> 16) & 1u);
    return (ushort)(b >> 16);
}
__device__ __forceinline__ float bf2f(ushort u) {
    return __uint_as_float(((unsigned)u) << 16);
}

// ---------------- small kernels ----------------

__global__ void zero_i32(int* __restrict__ p, int n) {
    int i = blockIdx.x * 256 + threadIdx.x;
    if (i < n) p[i] = 0;
}

__global__ void deg_cnt_kernel(const int* __restrict__ dst, int* __restrict__ cnt, int E) {
    int base = blockIdx.x * 1024 + threadIdx.x;
    #pragma unroll
    for (int q = 0; q < 4; ++q) {
        int e = base + q * 256;
        if (e < E) atomicAdd(&cnt[dst[e]], 1);
    }
}

__global__ void dinv_kernel(const int* __restrict__ cnt, float* __restrict__ dinv, int N) {
    int i = blockIdx.x * 256 + threadIdx.x;
    if (i < N) dinv[i] = rsqrtf((float)cnt[i] + 1.0f);
}

// ---------------- CSR build: bucketed histogram + binned counting sort ----------------

// Stage 0: per-block 256-bucket LDS histogram of dst>>8, then ONE bucketed global
// atomicAdd per bucket (782 adds/address, L2-resident — cheap; no partial buffer).
__global__ __launch_bounds__(256) void hist_part_kernel(const int* __restrict__ dst,
                                                        int* __restrict__ bucket_cnt, int E) {
    __shared__ int lcnt[256];
    int t = threadIdx.x;
    int base = blockIdx.x * ASORT_CHUNK;
    lcnt[t] = 0;
    __syncthreads();
    #pragma unroll
    for (int j = 0; j < 8; ++j) {
        int e = base + j * 256 + t;
        if (e < E) atomicAdd(&lcnt[((unsigned)dst[e]) >> 8], 1);
    }
    __syncthreads();
    int v = lcnt[t];
    if (v > 0) atomicAdd(&bucket_cnt[t], v);
}

// Stage 1 (1 block): exclusive scan of 256 bucket counts -> bucket_base[257], seed bucket_pos.
__global__ __launch_bounds__(256) void bucket_scan_kernel(const int* __restrict__ bucket_cnt,
                                                          int* __restrict__ bucket_base,
                                                          int* __restrict__ bucket_pos, int E) {
    __shared__ int sc[256];
    int t = threadIdx.x;
    int sum = bucket_cnt[t];
    sc[t] = sum;
    __syncthreads();
    for (int off = 1; off < 256; off <<= 1) {
        int u = (t >= off) ? sc[t - off] : 0;
        __syncthreads();
        sc[t] += u;
        __syncthreads();
    }
    int excl = sc[t] - sum;
    bucket_base[t] = excl;
    bucket_pos[t]  = excl;
    if (t == 255) bucket_base[256] = sc[255];   // == E
}

// Pass A: per-block LDS counting sort by bucket (dst>>8), flushed as contiguous runs
// into the bucket's region. Record packs src|dst<<16 (4B, N<=65536).
__global__ __launch_bounds__(256) void binA_kernel(const int* __restrict__ src,
                                                   const int* __restrict__ dst,
                                                   int* __restrict__ bucket_pos,
                                                   unsigned* __restrict__ binned, int E) {
    __shared__ int lcnt[256];
    __shared__ int lbase[256];
    __shared__ int gbase[256];
    __shared__ int sc[256];
    __shared__ unsigned sorted[ASORT_CHUNK];
    int t = threadIdx.x;
    int base = blockIdx.x * ASORT_CHUNK;
    lcnt[t] = 0;
    __syncthreads();
    unsigned pk[8];
    short bb[8];
    short mi[8];
    #pragma unroll
    for (int j = 0; j < 8; ++j) {
        int e = base + j * 256 + t;
        if (e < E) {
            unsigned s = (unsigned)src[e];
            unsigned d = (unsigned)dst[e];
            pk[j] = s | (d << 16);
            int b = (int)(d >> 8);
            bb[j] = (short)b;
            mi[j] = (short)atomicAdd(&lcnt[b], 1);
        } else {
            bb[j] = -1;
        }
    }
    __syncthreads();
    int v = lcnt[t];
    sc[t] = v;
    __syncthreads();
    #pragma unroll
    for (int off = 1; off < 256; off <<= 1) {
        int u = (t >= off) ? sc[t - off] : 0;
        __syncthreads();
        sc[t] += u;
        __syncthreads();
    }
    lbase[t] = sc[t] - v;                       // exclusive prefix
    if (v > 0) gbase[t] = atomicAdd(&bucket_pos[t], v);
    __syncthreads();
    #pragma unroll
    for (int j = 0; j < 8; ++j)
        if (bb[j] >= 0) sorted[lbase[(int)bb[j]] + (int)mi[j]] = pk[j];
    int tot = sc[255];
    __syncthreads();
    for (int i = t; i < tot; i += 256) {
        unsigned vv = sorted[i];
        int b = (int)(vv >> 24);                // dst>>8 (dst < 65536)
        binned[gbase[b] + (i - lbase[b])] = vv;
    }
}

// Pass B: one block per bucket. Pass 1: LDS per-node histogram + scan -> writes
// row_start/cnt/dinv for its 256 nodes (no global atomics). Pass 2: scatter rec4
// within the bucket's ~32KB region (L1/L2-hot second read). rec4[p] = src.
__global__ __launch_bounds__(256) void binB_kernel(const int* __restrict__ bucket_base,
                                                   const unsigned* __restrict__ binned,
                                                   int* __restrict__ rec4,
                                                   int* __restrict__ row_start,
                                                   int* __restrict__ cnt,
                                                   float* __restrict__ dinv, int N) {
    __shared__ int lcnt[256];
    __shared__ int sc[256];
    __shared__ int lstart[256];
    __shared__ int loff[256];
    int t = threadIdx.x;
    int d0 = blockIdx.x << 8;
    int start = bucket_base[blockIdx.x];
    int end   = bucket_base[blockIdx.x + 1];
    lcnt[t] = 0;
    __syncthreads();
    // pass 1: per-node histogram of this bucket's edges
    for (int i = start + t; i < end; i += 256)
        atomicAdd(&lcnt[(binned[i] >> 16) & 0xffu], 1);
    __syncthreads();
    int v = lcnt[t];
    sc[t] = v;
    __syncthreads();
    for (int off = 1; off < 256; off <<= 1) {
        int u = (t >= off) ? sc[t - off] : 0;
        __syncthreads();
        sc[t] += u;
        __syncthreads();
    }
    int st = start + sc[t] - v;                  // row start for node d0+t
    lstart[t] = st;
    loff[t] = 0;
    if (d0 + t < N) {
        row_start[d0 + t] = st;
        cnt[d0 + t] = v;
        dinv[d0 + t] = rsqrtf((float)v + 1.0f);
    }
    __syncthreads();
    // pass 2: scatter src into CSR slots
    int i = start + t;
    for (; i + 768 < end; i += 1024) {
        unsigned v0 = binned[i];
        unsigned v1 = binned[i + 256];
        unsigned v2 = binned[i + 512];
        unsigned v3 = binned[i + 768];
        int dA = (int)((v0 >> 16) & 0xffu); int kA = atomicAdd(&loff[dA], 1);
        rec4[lstart[dA] + kA] = (int)(v0 & 0xffffu);
        int dB = (int)((v1 >> 16) & 0xffu); int kB = atomicAdd(&loff[dB], 1);
        rec4[lstart[dB] + kB] = (int)(v1 & 0xffffu);
        int dC = (int)((v2 >> 16) & 0xffu); int kC = atomicAdd(&loff[dC], 1);
        rec4[lstart[dC] + kC] = (int)(v2 & 0xffffu);
        int dD = (int)((v3 >> 16) & 0xffu); int kD = atomicAdd(&loff[dD], 1);
        rec4[lstart[dD] + kD] = (int)(v3 & 0xffffu);
    }
    for (; i < end; i += 256) {
        unsigned v4 = binned[i];
        int d = (int)((v4 >> 16) & 0xffu);
        int k = atomicAdd(&loff[d], 1);
        rec4[lstart[d] + k] = (int)(v4 & 0xffffu);
    }
}

// ---------------- gather-side aggregation: 4 edges per wave-instruction ----------------
// Wave = 1 node. Lane L: g = L>>4 (edge slot), q = L&15 (feature quad, 4 bf16 = 8B).
// rec4 holds src only; w = dinv[src]*dinv[node] recomputed (dinv is L2-resident).

// layer 1: gather bf16 h1 (cols [128..191]); write bf16 hrelu = relu(acc + dv^2*own + b1)
__global__ void gather_relu_kernel(const int* __restrict__ rec4, const int* __restrict__ row_start,
                                   const int* __restrict__ cnt, const float* __restrict__ dinv,
                                   const float* __restrict__ b1, float* __restrict__ out, int N) {
    int node = blockIdx.x * 4 + (threadIdx.x >> 6);
    if (node >= N) return;
    int L = threadIdx.x & 63;
    int g = L >> 4;
    int q = L & 15;
    const ushort* hb = (const ushort*)out;
    int beg = row_start[node];
    int n   = cnt[node];
    float dvd = dinv[node];
    float4 acc = make_float4(0.f, 0.f, 0.f, 0.f);
    for (int i = 0; i < n; i += 16) {
        #pragma unroll
        for (int u = 0; u < 4; ++u) {
            int idx = i + u * 4 + g;
            int sidx = node;
            float w = 0.f;
            if (idx < n) {
                sidx = rec4[beg + idx];
                w = dinv[sidx] * dvd;
            }
            uint2 hv = *(const uint2*)(hb + (size_t)sidx * 256 + 128 + q * 4);
            acc.x = fmaf(bf2f((ushort)(hv.x & 0xffffu)), w, acc.x);
            acc.y = fmaf(bf2f((ushort)(hv.x >> 16)),     w, acc.y);
            acc.z = fmaf(bf2f((ushort)(hv.y & 0xffffu)), w, acc.z);
            acc.w = fmaf(bf2f((ushort)(hv.y >> 16)),     w, acc.w);
        }
    }
    acc.x += __shfl_xor(acc.x, 16, 64);
    acc.y += __shfl_xor(acc.y, 16, 64);
    acc.z += __shfl_xor(acc.z, 16, 64);
    acc.w += __shfl_xor(acc.w, 16, 64);
    acc.x += __shfl_xor(acc.x, 32, 64);
    acc.y += __shfl_xor(acc.y, 32, 64);
    acc.z += __shfl_xor(acc.z, 32, 64);
    acc.w += __shfl_xor(acc.w, 32, 64);
    if (L < 16) {
        float dv2 = dvd * dvd;
        uint2 ho = *(const uint2*)(hb + (size_t)node * 256 + 128 + q * 4);
        float4 b = *(const float4*)&b1[q * 4];
        float r0 = fmaxf(acc.x + dv2 * bf2f((ushort)(ho.x & 0xffffu)) + b.x, 0.f);
        float r1 = fmaxf(acc.y + dv2 * bf2f((ushort)(ho.x >> 16))     + b.y, 0.f);
        float r2 = fmaxf(acc.z + dv2 * bf2f((ushort)(ho.y & 0xffffu)) + b.z, 0.f);
        float r3 = fmaxf(acc.w + dv2 * bf2f((ushort)(ho.y >> 16))     + b.w, 0.f);
        ushort4 st = {f2bf(r0), f2bf(r1), f2bf(r2), f2bf(r3)};
        *(ushort4*)((ushort*)out + (size_t)node * 256 + 192 + q * 4) = st;
    }
}

// layer 2: gather bf16 hrelu (cols [192..255]); write fp32 combined to float[0..63]
__global__ void gather_comb_kernel(const int* __restrict__ rec4, const int* __restrict__ row_start,
                                   const int* __restrict__ cnt, const float* __restrict__ dinv,
                                   float* __restrict__ out, int N) {
    int node = blockIdx.x * 4 + (threadIdx.x >> 6);
    if (node >= N) return;
    int L = threadIdx.x & 63;
    int g = L >> 4;
    int q = L & 15;
    const ushort* hb = (const ushort*)out;
    int beg = row_start[node];
    int n   = cnt[node];
    float dvd = dinv[node];
    float4 acc = make_float4(0.f, 0.f, 0.f, 0.f);
    for (int i = 0; i < n; i += 16) {
        #pragma unroll
        for (int u = 0; u < 4; ++u) {
            int idx = i + u * 4 + g;
            int sidx = node;
            float w = 0.f;
            if (idx < n) {
                sidx = rec4[beg + idx];
                w = dinv[sidx] * dvd;
            }
            uint2 hv = *(const uint2*)(hb + (size_t)sidx * 256 + 192 + q * 4);
            acc.x = fmaf(bf2f((ushort)(hv.x & 0xffffu)), w, acc.x);
            acc.y = fmaf(bf2f((ushort)(hv.x >> 16)),     w, acc.y);
            acc.z = fmaf(bf2f((ushort)(hv.y & 0xffffu)), w, acc.z);
            acc.w = fmaf(bf2f((ushort)(hv.y >> 16)),     w, acc.w);
        }
    }
    acc.x += __shfl_xor(acc.x, 16, 64);
    acc.y += __shfl_xor(acc.y, 16, 64);
    acc.z += __shfl_xor(acc.z, 16, 64);
    acc.w += __shfl_xor(acc.w, 16, 64);
    acc.x += __shfl_xor(acc.x, 32, 64);
    acc.y += __shfl_xor(acc.y, 32, 64);
    acc.z += __shfl_xor(acc.z, 32, 64);
    acc.w += __shfl_xor(acc.w, 32, 64);
    if (L < 16) {
        float dv2 = dvd * dvd;
        uint2 ho = *(const uint2*)(hb + (size_t)node * 256 + 192 + q * 4);
        float4 o;
        o.x = acc.x + dv2 * bf2f((ushort)(ho.x & 0xffffu));
        o.y = acc.y + dv2 * bf2f((ushort)(ho.x >> 16));
        o.z = acc.z + dv2 * bf2f((ushort)(ho.y & 0xffffu));
        o.w = acc.w + dv2 * bf2f((ushort)(ho.y >> 16));
        *(float4*)&out[(size_t)node * FO + q * 4] = o;
    }
}

// ---------------- dense kernels: register-tiled SGEMM ----------------

// mm1: h1 = x @ W1 -> bf16 at ushort[128..191] of each row (plain, unscaled).
__global__ __launch_bounds__(256) void mm1_tiled(const float* __restrict__ x,
                                                 const float* __restrict__ W1,
                                                 float* __restrict__ out, int N) {
    __shared__ float xs[32][128];
    __shared__ float ws[32][64];
    int tid = threadIdx.x;
    int R0  = blockIdx.x * 128;
    int ty  = tid >> 3;
    int tx  = tid & 7;
    float acc[4][8];
    #pragma unroll
    for (int i = 0; i < 4; ++i)
        #pragma unroll
        for (int j = 0; j < 8; ++j) acc[i][j] = 0.f;

    int sr = tid >> 1;
    int sk = (tid & 1) * 16;
    bool row_ok = (R0 + sr) < N;
    const float* xrow = x + (size_t)(R0 + sr) * FI;

    for (int k0 = 0; k0 < FI; k0 += 32) {
        __syncthreads();
        #pragma unroll
        for (int q = 0; q < 4; ++q) {
            float4 v = row_ok ? *(const float4*)&xrow[k0 + sk + q * 4]
                              : make_float4(0.f, 0.f, 0.f, 0.f);
            xs[sk + q * 4 + 0][sr] = v.x;
            xs[sk + q * 4 + 1][sr] = v.y;
            xs[sk + q * 4 + 2][sr] = v.z;
            xs[sk + q * 4 + 3][sr] = v.w;
        }
        {
            int f = tid * 2;
            *(float4*)&ws[0][0 + f * 4]     = *(const float4*)&W1[(size_t)k0 * 64 + f * 4];
            *(float4*)&ws[0][0 + f * 4 + 4] = *(const float4*)&W1[(size_t)k0 * 64 + f * 4 + 4];
        }
        __syncthreads();
        #pragma unroll 4
        for (int k = 0; k < 32; ++k) {
            float4 a  = *(const float4*)&xs[k][ty * 4];
            float4 bl = *(const float4*)&ws[k][tx * 4];
            float4 bh = *(const float4*)&ws[k][32 + tx * 4];
            float av[4] = {a.x, a.y, a.z, a.w};
            float bv[8] = {bl.x, bl.y, bl.z, bl.w, bh.x, bh.y, bh.z, bh.w};
            #pragma unroll
            for (int i = 0; i < 4; ++i)
                #pragma unroll
                for (int j = 0; j < 8; ++j)
                    acc[i][j] = fmaf(av[i], bv[j], acc[i][j]);
        }
    }
    #pragma unroll
    for (int i = 0; i < 4; ++i) {
        int row = R0 + ty * 4 + i;
        if (row < N) {
            ushort* ob = (ushort*)out + (size_t)row * 256 + 128;
            ushort4 lo = {f2bf(acc[i][0]), f2bf(acc[i][1]), f2bf(acc[i][2]), f2bf(acc[i][3])};
            ushort4 hi = {f2bf(acc[i][4]), f2bf(acc[i][5]), f2bf(acc[i][6]), f2bf(acc[i][7])};
            *(ushort4*)&ob[tx * 4]      = lo;
            *(ushort4*)&ob[32 + tx * 4] = hi;
        }
    }
}

// mm2: out_row = combined(float[0..63]) @ W2 + b2, in place.
__global__ __launch_bounds__(256) void mm2_tiled(const float* __restrict__ W2,
                                                 const float* __restrict__ b2,
                                                 float* __restrict__ out, int N) {
    __shared__ float xs[64][68];
    __shared__ float ws[64][128];
    int tid = threadIdx.x;
    int R0  = blockIdx.x * 64;
    int ty  = tid >> 4;
    int tx  = tid & 15;

    {
        int sr = tid >> 2;
        int l4 = tid & 3;
        int grow = R0 + sr;
        bool ok = grow < N;
        const float* orow = out + (size_t)grow * FO;
        #pragma unroll
        for (int q = 0; q < 4; ++q) {
            int j0 = (l4 + 4 * q) * 4;
            float4 a = ok ? *(const float4*)&orow[j0] : make_float4(0.f, 0.f, 0.f, 0.f);
            xs[j0 + 0][sr] = a.x;
            xs[j0 + 1][sr] = a.y;
            xs[j0 + 2][sr] = a.z;
            xs[j0 + 3][sr] = a.w;
        }
    }
    #pragma unroll
    for (int q = 0; q < 8; ++q) {
        int f = tid + q * 256;
        *(float4*)&ws[f >> 5][(f & 31) * 4] = *(const float4*)&W2[(size_t)f * 4];
    }
    __syncthreads();

    float acc[4][8];
    #pragma unroll
    for (int i = 0; i < 4; ++i)
        #pragma unroll
        for (int j = 0; j < 8; ++j) acc[i][j] = 0.f;

    #pragma unroll 4
    for (int k = 0; k < FH; ++k) {
        float4 a  = *(const float4*)&xs[k][ty * 4];
        float4 bl = *(const float4*)&ws[k][tx * 4];
        float4 bh = *(const float4*)&ws[k][64 + tx * 4];
        float av[4] = {a.x, a.y, a.z, a.w};
        float bv[8] = {bl.x, bl.y, bl.z, bl.w, bh.x, bh.y, bh.z, bh.w};
        #pragma unroll
        for (int i = 0; i < 4; ++i)
            #pragma unroll
            for (int j = 0; j < 8; ++j)
                acc[i][j] = fmaf(av[i], bv[j], acc[i][j]);
    }

    float4 b2l = *(const float4*)&b2[tx * 4];
    float4 b2h = *(const float4*)&b2[64 + tx * 4];
    #pragma unroll
    for (int i = 0; i < 4; ++i) {
        int row = R0 + ty * 4 + i;
        if (row < N) {
            float* o = out + (size_t)row * FO;
            *(float4*)&o[tx * 4] = make_float4(acc[i][0] + b2l.x, acc[i][1] + b2l.y,
                                               acc[i][2] + b2l.z, acc[i][3] + b2l.w);
            *(float4*)&o[64 + tx * 4] = make_float4(acc[i][4] + b2h.x, acc[i][5] + b2h.y,
                                                    acc[i][6] + b2h.z, acc[i][7] + b2h.w);
        }
    }
}

// ---------------- fallback (atomic scatter) pieces — all fp32 ----------------

__global__ void expand_hs1_kernel(float* __restrict__ out, int N) {
    int row = blockIdx.x * 4 + (threadIdx.x >> 6);
    if (row >= N) return;
    int lane = threadIdx.x & 63;
    float v = bf2f(((const ushort*)out)[(size_t)row * 256 + 128 + lane]);
    out[(size_t)row * FO + FH + lane] = v;
}

__global__ void zero_half_kernel(float* __restrict__ out, int half, int N) {
    int i = blockIdx.x * 256 + threadIdx.x;
    if (i >= N * FH) return;
    out[(size_t)(i >> 6) * FO + half + (i & 63)] = 0.f;
}

__global__ void scatter_half_kernel(const int* __restrict__ src, const int* __restrict__ dst,
                                    const float* __restrict__ dinv, float* __restrict__ out,
                                    int rh, int wh, int E) {
    int e = blockIdx.x * 4 + (threadIdx.x >> 6);
    if (e >= E) return;
    int lane = threadIdx.x & 63;
    int s = src[e];
    int d = dst[e];
    float w = dinv[s] * dinv[d];
    atomicAdd(&out[(size_t)d * FO + wh + lane], out[(size_t)s * FO + rh + lane] * w);
}

// lower = relu(lower_agg + dv^2*upper_own + b1)
__global__ void finish1_kernel(float* __restrict__ out, const float* __restrict__ dinv,
                               const float* __restrict__ b1, int N) {
    int i = blockIdx.x * 256 + threadIdx.x;
    if (i >= N * FH) return;
    int row = i >> 6;
    int c   = i & 63;
    size_t base = (size_t)row * FO;
    float dv = dinv[row];
    out[base + c] = fmaxf(out[base + c] + dv * dv * out[base + FH + c] + b1[c], 0.f);
}

// lower = upper_agg + dv^2*lower_own   (combined for mm2)
__global__ void finish2_kernel(float* __restrict__ out, const float* __restrict__ dinv, int N) {
    int i = blockIdx.x * 256 + threadIdx.x;
    if (i >= N * FH) return;
    int row = i >> 6;
    int c   = i & 63;
    size_t base = (size_t)row * FO;
    float dv = dinv[row];
    out[base + c] = out[base + FH + c] + dv * dv * out[base + c];
}

extern "C" void kernel_launch(void* const* d_in, const int* in_sizes, int n_in,
                              void* d_out, int out_size, void* d_ws, size_t ws_size,
                              hipStream_t stream) {
    const float* x  = (const float*)d_in[0];
    const int*   ei = (const int*)d_in[1];
    const float* W1 = (const float*)d_in[2];
    const float* b1 = (const float*)d_in[3];
    const float* W2 = (const float*)d_in[4];
    const float* b2 = (const float*)d_in[5];
    float* out = (float*)d_out;

    int N = in_sizes[0] / FI;     // 50000
    int E = in_sizes[1] / 2;      // 1600000
    const int* src = ei;
    const int* dst = ei + E;

    char* w = (char*)d_ws;
    float* dinv        = (float*)w;      w += (size_t)N * 4;
    int*   cnt         = (int*)w;        w += (size_t)N * 4;
    int*   row_start   = (int*)w;        w += (size_t)N * 4;
    int*   bucket_cnt  = (int*)w;        w += 256 * 4;
    int*   bucket_pos  = (int*)w;        w += 256 * 4;
    int*   bucket_base = (int*)w;        w += 260 * 4;
    unsigned* binned   = (unsigned*)w;   w += (size_t)E * 4;
    int*   rec4        = (int*)w;        w += (size_t)E * 4;
    size_t need = (size_t)(w - (char*)d_ws);   // ~13.4 MB

    int nblkA = (E + ASORT_CHUNK - 1) / ASORT_CHUNK;   // 782
    int nbk   = (N + 255) >> 8;                        // 196 buckets for N=50000

    if (ws_size >= need && N <= 65536) {
        zero_i32<<<1, 256, 0, stream>>>(bucket_cnt, 256);
        hist_part_kernel<<<nblkA, 256, 0, stream>>>(dst, bucket_cnt, E);
        bucket_scan_kernel<<<1, 256, 0, stream>>>(bucket_cnt, bucket_base, bucket_pos, E);
        binA_kernel<<<nblkA, 256, 0, stream>>>(src, dst, bucket_pos, binned, E);
        binB_kernel<<<nbk, 256, 0, stream>>>(bucket_base, binned, rec4, row_start, cnt, dinv, N);

        mm1_tiled<<<(N + 127) / 128, 256, 0, stream>>>(x, W1, out, N);
        gather_relu_kernel<<<(N + 3) / 4, 256, 0, stream>>>(rec4, row_start, cnt, dinv, b1, out, N);
        gather_comb_kernel<<<(N + 3) / 4, 256, 0, stream>>>(rec4, row_start, cnt, dinv, out, N);
        mm2_tiled<<<(N + 63) / 64, 256, 0, stream>>>(W2, b2, out, N);
    } else {
        // fallback: atomic scatter path, all fp32
        zero_i32<<<(N + 255) / 256, 256, 0, stream>>>(cnt, N);
        deg_cnt_kernel<<<(E + 1023) / 1024, 256, 0, stream>>>(dst, cnt, E);
        dinv_kernel<<<(N + 255) / 256, 256, 0, stream>>>(cnt, dinv, N);
        mm1_tiled<<<(N + 127) / 128, 256, 0, stream>>>(x, W1, out, N);
        expand_hs1_kernel<<<(N + 3) / 4, 256, 0, stream>>>(out, N);
        zero_half_kernel<<<((N * FH) + 255) / 256, 256, 0, stream>>>(out, 0, N);
        scatter_half_kernel<<<(E + 3) / 4, 256, 0, stream>>>(src, dst, dinv, out, FH, 0, E);
        finish1_kernel<<<((N * FH) + 255) / 256, 256, 0, stream>>>(out, dinv, b1, N);
        zero_half_kernel<<<((N * FH) + 255) / 256, 256, 0, stream>>>(out, FH, N);
        scatter_half_kernel<<<(E + 3) / 4, 256, 0, stream>>>(src, dst, dinv, out, 0, FH, E);
        finish2_kernel<<<((N * FH) + 255) / 256, 256, 0, stream>>>(out, dinv, N);
        mm2_tiled<<<(N + 63) / 64, 256, 0, stream>>>(W2, b2, out, N);
    }
}

// Round 5
// 275.804 us; speedup vs baseline: 1.4524x; 1.1535x over previous
//
#include <hip/hip_runtime.h>

#define FI 256
#define FH 64
#define FO 128
#define ASORT_CHUNK 2048
// ushort-view row stride 256: bf16 h1 at ushort[128..191], bf16 hrelu at [192..255],
// fp32 combined at float[0..63].

__device__ __forceinline__ ushort f2bf(float x) {   // fp32 -> bf16 RNE
    unsigned b = __float_as_uint(x);
    b += 0x7fffu + ((b >> 16) & 1u);
    return (ushort)(b >> 16);
}
__device__ __forceinline__ float bf2f(ushort u) {
    return __uint_as_float(((unsigned)u) << 16);
}

// ---------------- small kernels ----------------

__global__ void zero_i32(int* __restrict__ p, int n) {
    int i = blockIdx.x * 256 + threadIdx.x;
    if (i < n) p[i] = 0;
}

__global__ void deg_cnt_kernel(const int* __restrict__ dst, int* __restrict__ cnt, int E) {
    int base = blockIdx.x * 1024 + threadIdx.x;
    #pragma unroll
    for (int q = 0; q < 4; ++q) {
        int e = base + q * 256;
        if (e < E) atomicAdd(&cnt[dst[e]], 1);
    }
}

__global__ void dinv_kernel(const int* __restrict__ cnt, float* __restrict__ dinv, int N) {
    int i = blockIdx.x * 256 + threadIdx.x;
    if (i < N) dinv[i] = rsqrtf((float)cnt[i] + 1.0f);
}

// ---------------- CSR build: bucketed histogram + binned counting sort ----------------

__global__ __launch_bounds__(256) void hist_part_kernel(const int* __restrict__ dst,
                                                        int* __restrict__ bucket_cnt, int E) {
    __shared__ int lcnt[256];
    int t = threadIdx.x;
    int base = blockIdx.x * ASORT_CHUNK;
    lcnt[t] = 0;
    __syncthreads();
    #pragma unroll
    for (int j = 0; j < 8; ++j) {
        int e = base + j * 256 + t;
        if (e < E) atomicAdd(&lcnt[((unsigned)dst[e]) >> 8], 1);
    }
    __syncthreads();
    int v = lcnt[t];
    if (v > 0) atomicAdd(&bucket_cnt[t], v);
}

__global__ __launch_bounds__(256) void bucket_scan_kernel(const int* __restrict__ bucket_cnt,
                                                          int* __restrict__ bucket_base,
                                                          int* __restrict__ bucket_pos, int E) {
    __shared__ int sc[256];
    int t = threadIdx.x;
    int sum = bucket_cnt[t];
    sc[t] = sum;
    __syncthreads();
    for (int off = 1; off < 256; off <<= 1) {
        int u = (t >= off) ? sc[t - off] : 0;
        __syncthreads();
        sc[t] += u;
        __syncthreads();
    }
    int excl = sc[t] - sum;
    bucket_base[t] = excl;
    bucket_pos[t]  = excl;
    if (t == 255) bucket_base[256] = sc[255];   // == E
}

// Pass A: per-block LDS counting sort by bucket (dst>>8), flushed as contiguous runs.
__global__ __launch_bounds__(256) void binA_kernel(const int* __restrict__ src,
                                                   const int* __restrict__ dst,
                                                   int* __restrict__ bucket_pos,
                                                   unsigned* __restrict__ binned, int E) {
    __shared__ int lcnt[256];
    __shared__ int lbase[256];
    __shared__ int gbase[256];
    __shared__ int sc[256];
    __shared__ unsigned sorted[ASORT_CHUNK];
    int t = threadIdx.x;
    int base = blockIdx.x * ASORT_CHUNK;
    lcnt[t] = 0;
    __syncthreads();
    unsigned pk[8];
    short bb[8];
    short mi[8];
    #pragma unroll
    for (int j = 0; j < 8; ++j) {
        int e = base + j * 256 + t;
        if (e < E) {
            unsigned s = (unsigned)src[e];
            unsigned d = (unsigned)dst[e];
            pk[j] = s | (d << 16);
            int b = (int)(d >> 8);
            bb[j] = (short)b;
            mi[j] = (short)atomicAdd(&lcnt[b], 1);
        } else {
            bb[j] = -1;
        }
    }
    __syncthreads();
    int v = lcnt[t];
    sc[t] = v;
    __syncthreads();
    #pragma unroll
    for (int off = 1; off < 256; off <<= 1) {
        int u = (t >= off) ? sc[t - off] : 0;
        __syncthreads();
        sc[t] += u;
        __syncthreads();
    }
    lbase[t] = sc[t] - v;                       // exclusive prefix
    if (v > 0) gbase[t] = atomicAdd(&bucket_pos[t], v);
    __syncthreads();
    #pragma unroll
    for (int j = 0; j < 8; ++j)
        if (bb[j] >= 0) sorted[lbase[(int)bb[j]] + (int)mi[j]] = pk[j];
    int tot = sc[255];
    __syncthreads();
    for (int i = t; i < tot; i += 256) {
        unsigned vv = sorted[i];
        int b = (int)(vv >> 24);                // dst>>8 (dst < 65536)
        binned[gbase[b] + (i - lbase[b])] = vv;
    }
}

// Pass B: one block per bucket; per-node histogram+scan in LDS, writes row_start/cnt/dinv,
// then scatters rec4 (src-only) inside the bucket's ~32KB region.
__global__ __launch_bounds__(256) void binB_kernel(const int* __restrict__ bucket_base,
                                                   const unsigned* __restrict__ binned,
                                                   int* __restrict__ rec4,
                                                   int* __restrict__ row_start,
                                                   int* __restrict__ cnt,
                                                   float* __restrict__ dinv, int N) {
    __shared__ int lcnt[256];
    __shared__ int sc[256];
    __shared__ int lstart[256];
    __shared__ int loff[256];
    int t = threadIdx.x;
    int d0 = blockIdx.x << 8;
    int start = bucket_base[blockIdx.x];
    int end   = bucket_base[blockIdx.x + 1];
    lcnt[t] = 0;
    __syncthreads();
    for (int i = start + t; i < end; i += 256)
        atomicAdd(&lcnt[(binned[i] >> 16) & 0xffu], 1);
    __syncthreads();
    int v = lcnt[t];
    sc[t] = v;
    __syncthreads();
    for (int off = 1; off < 256; off <<= 1) {
        int u = (t >= off) ? sc[t - off] : 0;
        __syncthreads();
        sc[t] += u;
        __syncthreads();
    }
    int st = start + sc[t] - v;                  // row start for node d0+t
    lstart[t] = st;
    loff[t] = 0;
    if (d0 + t < N) {
        row_start[d0 + t] = st;
        cnt[d0 + t] = v;
        dinv[d0 + t] = rsqrtf((float)v + 1.0f);
    }
    __syncthreads();
    int i = start + t;
    for (; i + 768 < end; i += 1024) {
        unsigned v0 = binned[i];
        unsigned v1 = binned[i + 256];
        unsigned v2 = binned[i + 512];
        unsigned v3 = binned[i + 768];
        int dA = (int)((v0 >> 16) & 0xffu); int kA = atomicAdd(&loff[dA], 1);
        rec4[lstart[dA] + kA] = (int)(v0 & 0xffffu);
        int dB = (int)((v1 >> 16) & 0xffu); int kB = atomicAdd(&loff[dB], 1);
        rec4[lstart[dB] + kB] = (int)(v1 & 0xffffu);
        int dC = (int)((v2 >> 16) & 0xffu); int kC = atomicAdd(&loff[dC], 1);
        rec4[lstart[dC] + kC] = (int)(v2 & 0xffffu);
        int dD = (int)((v3 >> 16) & 0xffu); int kD = atomicAdd(&loff[dD], 1);
        rec4[lstart[dD] + kD] = (int)(v3 & 0xffffu);
    }
    for (; i < end; i += 256) {
        unsigned v4 = binned[i];
        int d = (int)((v4 >> 16) & 0xffu);
        int k = atomicAdd(&loff[d], 1);
        rec4[lstart[d] + k] = (int)(v4 & 0xffffu);
    }
}

// ---------------- gather-side aggregation, v2 ----------------
// Wave = 1 node. Lane L: g = L>>3 (8 edge slots), q = L&7 (feature octet, 8 bf16 = 16B).
// Per 64-edge chunk: all lanes cooperatively load rec4 (coalesced) + gather dinv ONCE;
// inner loop broadcasts (src, w) via __shfl — the only per-edge global access is the
// 16B feature gather, 8+ in flight per wave.

#define ACC8(hv, wt)                                                   \
    acc[0] = fmaf(__uint_as_float((hv).x << 16),         wt, acc[0]);  \
    acc[1] = fmaf(__uint_as_float((hv).x & 0xffff0000u), wt, acc[1]);  \
    acc[2] = fmaf(__uint_as_float((hv).y << 16),         wt, acc[2]);  \
    acc[3] = fmaf(__uint_as_float((hv).y & 0xffff0000u), wt, acc[3]);  \
    acc[4] = fmaf(__uint_as_float((hv).z << 16),         wt, acc[4]);  \
    acc[5] = fmaf(__uint_as_float((hv).z & 0xffff0000u), wt, acc[5]);  \
    acc[6] = fmaf(__uint_as_float((hv).w << 16),         wt, acc[6]);  \
    acc[7] = fmaf(__uint_as_float((hv).w & 0xffff0000u), wt, acc[7]);

// layer 1: gather bf16 h1 (ushort cols [128..191]); write bf16 hrelu = relu(acc + dv^2*own + b1)
__global__ void gather_relu_kernel(const int* __restrict__ rec4, const int* __restrict__ row_start,
                                   const int* __restrict__ cnt, const float* __restrict__ dinv,
                                   const float* __restrict__ b1, float* __restrict__ out, int N) {
    int node = blockIdx.x * 4 + (threadIdx.x >> 6);
    if (node >= N) return;
    int L = threadIdx.x & 63;
    int g = L >> 3;
    int q = L & 7;
    const ushort* hb = (const ushort*)out;
    int beg = row_start[node];
    int n   = cnt[node];
    float dvd = dinv[node];
    float acc[8] = {0.f, 0.f, 0.f, 0.f, 0.f, 0.f, 0.f, 0.f};
    for (int c0 = 0; c0 < n; c0 += 64) {
        int idx_l = c0 + L;
        int sreg = node;
        float wreg = 0.f;
        if (idx_l < n) {
            sreg = rec4[beg + idx_l];
            wreg = dinv[sreg] * dvd;
        }
        int m = n - c0; if (m > 64) m = 64;
        int umax = (m + 7) >> 3;          // lanes >= m carry w=0 -> safe zero contribution
        #pragma unroll 2
        for (int u = 0; u < umax; ++u) {
            int lane = u * 8 + g;
            int sidx  = __shfl(sreg, lane, 64);
            float wt  = __shfl(wreg, lane, 64);
            uint4 hv = *(const uint4*)(hb + (size_t)sidx * 256 + 128 + q * 8);
            ACC8(hv, wt)
        }
    }
    #pragma unroll
    for (int off = 8; off < 64; off <<= 1)
        #pragma unroll
        for (int j = 0; j < 8; ++j)
            acc[j] += __shfl_xor(acc[j], off, 64);
    if (L < 8) {
        float dv2 = dvd * dvd;
        uint4 ho = *(const uint4*)(hb + (size_t)node * 256 + 128 + q * 8);
        float4 bl = *(const float4*)&b1[q * 8];
        float4 bh = *(const float4*)&b1[q * 8 + 4];
        float r0 = fmaxf(acc[0] + dv2 * __uint_as_float(ho.x << 16)         + bl.x, 0.f);
        float r1 = fmaxf(acc[1] + dv2 * __uint_as_float(ho.x & 0xffff0000u) + bl.y, 0.f);
        float r2 = fmaxf(acc[2] + dv2 * __uint_as_float(ho.y << 16)         + bl.z, 0.f);
        float r3 = fmaxf(acc[3] + dv2 * __uint_as_float(ho.y & 0xffff0000u) + bl.w, 0.f);
        float r4 = fmaxf(acc[4] + dv2 * __uint_as_float(ho.z << 16)         + bh.x, 0.f);
        float r5 = fmaxf(acc[5] + dv2 * __uint_as_float(ho.z & 0xffff0000u) + bh.y, 0.f);
        float r6 = fmaxf(acc[6] + dv2 * __uint_as_float(ho.w << 16)         + bh.z, 0.f);
        float r7 = fmaxf(acc[7] + dv2 * __uint_as_float(ho.w & 0xffff0000u) + bh.w, 0.f);
        uint4 st;
        st.x = (unsigned)f2bf(r0) | ((unsigned)f2bf(r1) << 16);
        st.y = (unsigned)f2bf(r2) | ((unsigned)f2bf(r3) << 16);
        st.z = (unsigned)f2bf(r4) | ((unsigned)f2bf(r5) << 16);
        st.w = (unsigned)f2bf(r6) | ((unsigned)f2bf(r7) << 16);
        *(uint4*)((ushort*)out + (size_t)node * 256 + 192 + q * 8) = st;
    }
}

// layer 2: gather bf16 hrelu (ushort cols [192..255]); write fp32 combined to float[0..63]
__global__ void gather_comb_kernel(const int* __restrict__ rec4, const int* __restrict__ row_start,
                                   const int* __restrict__ cnt, const float* __restrict__ dinv,
                                   float* __restrict__ out, int N) {
    int node = blockIdx.x * 4 + (threadIdx.x >> 6);
    if (node >= N) return;
    int L = threadIdx.x & 63;
    int g = L >> 3;
    int q = L & 7;
    const ushort* hb = (const ushort*)out;
    int beg = row_start[node];
    int n   = cnt[node];
    float dvd = dinv[node];
    float acc[8] = {0.f, 0.f, 0.f, 0.f, 0.f, 0.f, 0.f, 0.f};
    for (int c0 = 0; c0 < n; c0 += 64) {
        int idx_l = c0 + L;
        int sreg = node;
        float wreg = 0.f;
        if (idx_l < n) {
            sreg = rec4[beg + idx_l];
            wreg = dinv[sreg] * dvd;
        }
        int m = n - c0; if (m > 64) m = 64;
        int umax = (m + 7) >> 3;
        #pragma unroll 2
        for (int u = 0; u < umax; ++u) {
            int lane = u * 8 + g;
            int sidx  = __shfl(sreg, lane, 64);
            float wt  = __shfl(wreg, lane, 64);
            uint4 hv = *(const uint4*)(hb + (size_t)sidx * 256 + 192 + q * 8);
            ACC8(hv, wt)
        }
    }
    #pragma unroll
    for (int off = 8; off < 64; off <<= 1)
        #pragma unroll
        for (int j = 0; j < 8; ++j)
            acc[j] += __shfl_xor(acc[j], off, 64);
    if (L < 8) {
        float dv2 = dvd * dvd;
        uint4 ho = *(const uint4*)(hb + (size_t)node * 256 + 192 + q * 8);
        float4 o0, o1;
        o0.x = acc[0] + dv2 * __uint_as_float(ho.x << 16);
        o0.y = acc[1] + dv2 * __uint_as_float(ho.x & 0xffff0000u);
        o0.z = acc[2] + dv2 * __uint_as_float(ho.y << 16);
        o0.w = acc[3] + dv2 * __uint_as_float(ho.y & 0xffff0000u);
        o1.x = acc[4] + dv2 * __uint_as_float(ho.z << 16);
        o1.y = acc[5] + dv2 * __uint_as_float(ho.z & 0xffff0000u);
        o1.z = acc[6] + dv2 * __uint_as_float(ho.w << 16);
        o1.w = acc[7] + dv2 * __uint_as_float(ho.w & 0xffff0000u);
        *(float4*)&out[(size_t)node * FO + q * 8]     = o0;
        *(float4*)&out[(size_t)node * FO + q * 8 + 4] = o1;
    }
}

// ---------------- dense kernels: register-tiled SGEMM ----------------

// mm1: h1 = x @ W1 -> bf16 at ushort[128..191] of each row (plain, unscaled).
__global__ __launch_bounds__(256) void mm1_tiled(const float* __restrict__ x,
                                                 const float* __restrict__ W1,
                                                 float* __restrict__ out, int N) {
    __shared__ float xs[32][128];
    __shared__ float ws[32][64];
    int tid = threadIdx.x;
    int R0  = blockIdx.x * 128;
    int ty  = tid >> 3;
    int tx  = tid & 7;
    float acc[4][8];
    #pragma unroll
    for (int i = 0; i < 4; ++i)
        #pragma unroll
        for (int j = 0; j < 8; ++j) acc[i][j] = 0.f;

    int sr = tid >> 1;
    int sk = (tid & 1) * 16;
    bool row_ok = (R0 + sr) < N;
    const float* xrow = x + (size_t)(R0 + sr) * FI;

    for (int k0 = 0; k0 < FI; k0 += 32) {
        __syncthreads();
        #pragma unroll
        for (int q = 0; q < 4; ++q) {
            float4 v = row_ok ? *(const float4*)&xrow[k0 + sk + q * 4]
                              : make_float4(0.f, 0.f, 0.f, 0.f);
            xs[sk + q * 4 + 0][sr] = v.x;
            xs[sk + q * 4 + 1][sr] = v.y;
            xs[sk + q * 4 + 2][sr] = v.z;
            xs[sk + q * 4 + 3][sr] = v.w;
        }
        {
            int f = tid * 2;
            *(float4*)&ws[0][0 + f * 4]     = *(const float4*)&W1[(size_t)k0 * 64 + f * 4];
            *(float4*)&ws[0][0 + f * 4 + 4] = *(const float4*)&W1[(size_t)k0 * 64 + f * 4 + 4];
        }
        __syncthreads();
        #pragma unroll 4
        for (int k = 0; k < 32; ++k) {
            float4 a  = *(const float4*)&xs[k][ty * 4];
            float4 bl = *(const float4*)&ws[k][tx * 4];
            float4 bh = *(const float4*)&ws[k][32 + tx * 4];
            float av[4] = {a.x, a.y, a.z, a.w};
            float bv[8] = {bl.x, bl.y, bl.z, bl.w, bh.x, bh.y, bh.z, bh.w};
            #pragma unroll
            for (int i = 0; i < 4; ++i)
                #pragma unroll
                for (int j = 0; j < 8; ++j)
                    acc[i][j] = fmaf(av[i], bv[j], acc[i][j]);
        }
    }
    #pragma unroll
    for (int i = 0; i < 4; ++i) {
        int row = R0 + ty * 4 + i;
        if (row < N) {
            ushort* ob = (ushort*)out + (size_t)row * 256 + 128;
            ushort4 lo = {f2bf(acc[i][0]), f2bf(acc[i][1]), f2bf(acc[i][2]), f2bf(acc[i][3])};
            ushort4 hi = {f2bf(acc[i][4]), f2bf(acc[i][5]), f2bf(acc[i][6]), f2bf(acc[i][7])};
            *(ushort4*)&ob[tx * 4]      = lo;
            *(ushort4*)&ob[32 + tx * 4] = hi;
        }
    }
}

// mm2: out_row = combined(float[0..63]) @ W2 + b2, in place.
__global__ __launch_bounds__(256) void mm2_tiled(const float* __restrict__ W2,
                                                 const float* __restrict__ b2,
                                                 float* __restrict__ out, int N) {
    __shared__ float xs[64][68];
    __shared__ float ws[64][128];
    int tid = threadIdx.x;
    int R0  = blockIdx.x * 64;
    int ty  = tid >> 4;
    int tx  = tid & 15;

    {
        int sr = tid >> 2;
        int l4 = tid & 3;
        int grow = R0 + sr;
        bool ok = grow < N;
        const float* orow = out + (size_t)grow * FO;
        #pragma unroll
        for (int q = 0; q < 4; ++q) {
            int j0 = (l4 + 4 * q) * 4;
            float4 a = ok ? *(const float4*)&orow[j0] : make_float4(0.f, 0.f, 0.f, 0.f);
            xs[j0 + 0][sr] = a.x;
            xs[j0 + 1][sr] = a.y;
            xs[j0 + 2][sr] = a.z;
            xs[j0 + 3][sr] = a.w;
        }
    }
    #pragma unroll
    for (int q = 0; q < 8; ++q) {
        int f = tid + q * 256;
        *(float4*)&ws[f >> 5][(f & 31) * 4] = *(const float4*)&W2[(size_t)f * 4];
    }
    __syncthreads();

    float acc[4][8];
    #pragma unroll
    for (int i = 0; i < 4; ++i)
        #pragma unroll
        for (int j = 0; j < 8; ++j) acc[i][j] = 0.f;

    #pragma unroll 4
    for (int k = 0; k < FH; ++k) {
        float4 a  = *(const float4*)&xs[k][ty * 4];
        float4 bl = *(const float4*)&ws[k][tx * 4];
        float4 bh = *(const float4*)&ws[k][64 + tx * 4];
        float av[4] = {a.x, a.y, a.z, a.w};
        float bv[8] = {bl.x, bl.y, bl.z, bl.w, bh.x, bh.y, bh.z, bh.w};
        #pragma unroll
        for (int i = 0; i < 4; ++i)
            #pragma unroll
            for (int j = 0; j < 8; ++j)
                acc[i][j] = fmaf(av[i], bv[j], acc[i][j]);
    }

    float4 b2l = *(const float4*)&b2[tx * 4];
    float4 b2h = *(const float4*)&b2[64 + tx * 4];
    #pragma unroll
    for (int i = 0; i < 4; ++i) {
        int row = R0 + ty * 4 + i;
        if (row < N) {
            float* o = out + (size_t)row * FO;
            *(float4*)&o[tx * 4] = make_float4(acc[i][0] + b2l.x, acc[i][1] + b2l.y,
                                               acc[i][2] + b2l.z, acc[i][3] + b2l.w);
            *(float4*)&o[64 + tx * 4] = make_float4(acc[i][4] + b2h.x, acc[i][5] + b2h.y,
                                                    acc[i][6] + b2h.z, acc[i][7] + b2h.w);
        }
    }
}

// ---------------- fallback (atomic scatter) pieces — all fp32 ----------------

__global__ void expand_hs1_kernel(float* __restrict__ out, int N) {
    int row = blockIdx.x * 4 + (threadIdx.x >> 6);
    if (row >= N) return;
    int lane = threadIdx.x & 63;
    float v = bf2f(((const ushort*)out)[(size_t)row * 256 + 128 + lane]);
    out[(size_t)row * FO + FH + lane] = v;
}

__global__ void zero_half_kernel(float* __restrict__ out, int half, int N) {
    int i = blockIdx.x * 256 + threadIdx.x;
    if (i >= N * FH) return;
    out[(size_t)(i >> 6) * FO + half + (i & 63)] = 0.f;
}

__global__ void scatter_half_kernel(const int* __restrict__ src, const int* __restrict__ dst,
                                    const float* __restrict__ dinv, float* __restrict__ out,
                                    int rh, int wh, int E) {
    int e = blockIdx.x * 4 + (threadIdx.x >> 6);
    if (e >= E) return;
    int lane = threadIdx.x & 63;
    int s = src[e];
    int d = dst[e];
    float w = dinv[s] * dinv[d];
    atomicAdd(&out[(size_t)d * FO + wh + lane], out[(size_t)s * FO + rh + lane] * w);
}

// lower = relu(lower_agg + dv^2*upper_own + b1)
__global__ void finish1_kernel(float* __restrict__ out, const float* __restrict__ dinv,
                               const float* __restrict__ b1, int N) {
    int i = blockIdx.x * 256 + threadIdx.x;
    if (i >= N * FH) return;
    int row = i >> 6;
    int c   = i & 63;
    size_t base = (size_t)row * FO;
    float dv = dinv[row];
    out[base + c] = fmaxf(out[base + c] + dv * dv * out[base + FH + c] + b1[c], 0.f);
}

// lower = upper_agg + dv^2*lower_own   (combined for mm2)
__global__ void finish2_kernel(float* __restrict__ out, const float* __restrict__ dinv, int N) {
    int i = blockIdx.x * 256 + threadIdx.x;
    if (i >= N * FH) return;
    int row = i >> 6;
    int c   = i & 63;
    size_t base = (size_t)row * FO;
    float dv = dinv[row];
    out[base + c] = out[base + FH + c] + dv * dv * out[base + c];
}

extern "C" void kernel_launch(void* const* d_in, const int* in_sizes, int n_in,
                              void* d_out, int out_size, void* d_ws, size_t ws_size,
                              hipStream_t stream) {
    const float* x  = (const float*)d_in[0];
    const int*   ei = (const int*)d_in[1];
    const float* W1 = (const float*)d_in[2];
    const float* b1 = (const float*)d_in[3];
    const float* W2 = (const float*)d_in[4];
    const float* b2 = (const float*)d_in[5];
    float* out = (float*)d_out;

    int N = in_sizes[0] / FI;     // 50000
    int E = in_sizes[1] / 2;      // 1600000
    const int* src = ei;
    const int* dst = ei + E;

    char* w = (char*)d_ws;
    float* dinv        = (float*)w;      w += (size_t)N * 4;
    int*   cnt         = (int*)w;        w += (size_t)N * 4;
    int*   row_start   = (int*)w;        w += (size_t)N * 4;
    int*   bucket_cnt  = (int*)w;        w += 256 * 4;
    int*   bucket_pos  = (int*)w;        w += 256 * 4;
    int*   bucket_base = (int*)w;        w += 260 * 4;
    unsigned* binned   = (unsigned*)w;   w += (size_t)E * 4;
    int*   rec4        = (int*)w;        w += (size_t)E * 4;
    size_t need = (size_t)(w - (char*)d_ws);   // ~13.4 MB

    int nblkA = (E + ASORT_CHUNK - 1) / ASORT_CHUNK;   // 782
    int nbk   = (N + 255) >> 8;                        // 196 buckets for N=50000

    if (ws_size >= need && N <= 65536) {
        zero_i32<<<1, 256, 0, stream>>>(bucket_cnt, 256);
        hist_part_kernel<<<nblkA, 256, 0, stream>>>(dst, bucket_cnt, E);
        bucket_scan_kernel<<<1, 256, 0, stream>>>(bucket_cnt, bucket_base, bucket_pos, E);
        binA_kernel<<<nblkA, 256, 0, stream>>>(src, dst, bucket_pos, binned, E);
        binB_kernel<<<nbk, 256, 0, stream>>>(bucket_base, binned, rec4, row_start, cnt, dinv, N);

        mm1_tiled<<<(N + 127) / 128, 256, 0, stream>>>(x, W1, out, N);
        gather_relu_kernel<<<(N + 3) / 4, 256, 0, stream>>>(rec4, row_start, cnt, dinv, b1, out, N);
        gather_comb_kernel<<<(N + 3) / 4, 256, 0, stream>>>(rec4, row_start, cnt, dinv, out, N);
        mm2_tiled<<<(N + 63) / 64, 256, 0, stream>>>(W2, b2, out, N);
    } else {
        // fallback: atomic scatter path, all fp32
        zero_i32<<<(N + 255) / 256, 256, 0, stream>>>(cnt, N);
        deg_cnt_kernel<<<(E + 1023) / 1024, 256, 0, stream>>>(dst, cnt, E);
        dinv_kernel<<<(N + 255) / 256, 256, 0, stream>>>(cnt, dinv, N);
        mm1_tiled<<<(N + 127) / 128, 256, 0, stream>>>(x, W1, out, N);
        expand_hs1_kernel<<<(N + 3) / 4, 256, 0, stream>>>(out, N);
        zero_half_kernel<<<((N * FH) + 255) / 256, 256, 0, stream>>>(out, 0, N);
        scatter_half_kernel<<<(E + 3) / 4, 256, 0, stream>>>(src, dst, dinv, out, FH, 0, E);
        finish1_kernel<<<((N * FH) + 255) / 256, 256, 0, stream>>>(out, dinv, b1, N);
        zero_half_kernel<<<((N * FH) + 255) / 256, 256, 0, stream>>>(out, FH, N);
        scatter_half_kernel<<<(E + 3) / 4, 256, 0, stream>>>(src, dst, dinv, out, 0, FH, E);
        finish2_kernel<<<((N * FH) + 255) / 256, 256, 0, stream>>>(out, dinv, N);
        mm2_tiled<<<(N + 63) / 64, 256, 0, stream>>>(W2, b2, out, N);
    }
}